// Round 7
// baseline (229.458 us; speedup 1.0000x reference)
//
#include <hip/hip_runtime.h>

typedef unsigned short u16;
typedef unsigned int   u32;
typedef __attribute__((ext_vector_type(8))) short short8;   // 8 bf16
typedef __attribute__((ext_vector_type(4))) float f32x4;

__device__ __forceinline__ u16 f2bf(float f) {
    union { float f; u32 i; } v; v.f = f;
    u32 x = v.i;
    return (u16)((x + 0x7fffu + ((x >> 16) & 1u)) >> 16);   // RNE
}
__device__ __forceinline__ float bf2f(u16 u) {
    union { u32 i; float f; } v; v.i = ((u32)u) << 16; return v.f;
}

// ============================================================
// K1 (fused): blocks [0,1024): conv + clip + sigmoid + mask -> vh/vl
//             blocks [1024,1056): transpose+split ft_w -> bth/btl
// ============================================================
__global__ __launch_bounds__(256) void k1_conv_split(
    const float* __restrict__ images,   // (1024,3,96,96)
    const float* __restrict__ conv_w,   // (8,3,3,3)
    const float* __restrict__ ft_w,     // (800,1024)
    u16* __restrict__ vh, u16* __restrict__ vl,     // (1024,800)
    u16* __restrict__ bth, u16* __restrict__ btl)   // (1024,800) n-major
{
    __shared__ float img_s[3][29][96];
    __shared__ float w[216];
    __shared__ float tile[32][33];

    int t = threadIdx.x;

    if (blockIdx.x >= 1024) {
        // ---- ft_w transpose + hi/lo split: 32 blocks, n0 = 32*blk ----
        int n0 = (blockIdx.x - 1024) * 32;
        int kk = t >> 5, nn = t & 31;
        for (int k0 = 0; k0 < 800; k0 += 32) {
            #pragma unroll
            for (int i = 0; i < 4; i++) {
                int k = kk + i * 8;
                tile[k][nn] = ft_w[(k0 + k) * 1024 + n0 + nn];
            }
            __syncthreads();
            int k = t & 31, n8 = t >> 5;
            #pragma unroll
            for (int i = 0; i < 4; i++) {
                int n = n8 + i * 8;
                float wv = tile[k][n];
                u16 hi = f2bf(wv);
                float lo = wv - bf2f(hi);
                bth[(n0 + n) * 800 + k0 + k] = hi;
                btl[(n0 + n) * 800 + k0 + k] = f2bf(lo);
            }
            __syncthreads();
        }
        return;
    }

    // ---- conv path: one block per image ----
    int b = blockIdx.x;
    if (t < 216) w[t] = conv_w[t];

    for (int i = t; i < 3 * 29 * 96; i += 256) {
        int ch  = i / (29 * 96);
        int rem = i - ch * (29 * 96);
        int lr  = rem / 96;
        int x   = rem - lr * 96;
        int ih  = 10 * ((lr + 1) / 3) + (lr + 1) % 3 - 1;
        img_s[ch][lr][x] = images[((b * 3 + ch) * 96 + ih) * 96 + x];
    }
    __syncthreads();

    for (int ridx = t; ridx < 800; ridx += 256) {
        int o  = ridx / 100;
        int p  = ridx - o * 100;
        int oh = p / 10;
        int ow = p - oh * 10;

        float sum = 0.0f;
        #pragma unroll
        for (int ic = 0; ic < 3; ic++) {
            const float* wc = &w[o * 27 + ic * 9];
            #pragma unroll
            for (int kh = 0; kh < 3; kh++) {
                int lr = 3 * oh + kh - 1;
                if (lr < 0) continue;
                #pragma unroll
                for (int kw = 0; kw < 3; kw++) {
                    int iw = ow * 10 + kw - 1;
                    if (iw < 0) continue;
                    sum = fmaf(img_s[ic][lr][iw], wc[kh * 3 + kw], sum);
                }
            }
        }
        float xc = fminf(fmaxf(sum, -1.0f), 1.0f);
        float binary = 1.0f / (1.0f + __expf(-10.0f * xc));
        float v = (binary > 0.5f) ? binary : 0.0f;
        u16 hi = f2bf(v);
        vh[b * 800 + ridx] = hi;
        vl[b * 800 + ridx] = f2bf(v - bf2f(hi));
    }
}

// ============================================================
// K2: l0 = clip(vals @ ft_w + ft_b, 0, 1), split-bf16 MFMA
// C = Ah*Bh + Ah*Bl + Al*Bh. Tile 64Mx32N, grid (32,16)=512 blocks
// (2 blocks/CU, 2 waves/SIMD). 4 waves: wave quadrant 32Mx16N,
// 2x1 frags of 16x16x32, BK=32, 25 k-iters.
// LDS rows padded to 40 u16 (80 B): 20-dword stride -> only free
// 2-way conflicts on b128 fragment reads.
// ============================================================
__global__ __launch_bounds__(256) void k2_mfma(
    const u16* __restrict__ Ah, const u16* __restrict__ Al,   // (1024,800)
    const u16* __restrict__ Bh, const u16* __restrict__ Bl,   // (1024,800) n-major
    const float* __restrict__ bias,
    float* __restrict__ C)                                    // (1024,1024)
{
    __shared__ u16 sAh[64 * 40], sAl[64 * 40];
    __shared__ u16 sBh[32 * 40], sBl[32 * 40];
    int t = threadIdx.x;
    int m0 = blockIdx.y * 64, n0 = blockIdx.x * 32;
    int w = t >> 6, lane = t & 63;
    int quad = lane >> 4, lo4 = lane & 15;
    int wm = (w >> 1) * 32, wn = (w & 1) * 16;

    // A staging: thread -> (row 0..63, chunk 0..3), both hi & lo
    int sr = t >> 2, sq = t & 3;
    const u16* gAh = Ah + (m0 + sr) * 800 + sq * 8;
    const u16* gAl = Al + (m0 + sr) * 800 + sq * 8;
    int adst = sr * 40 + sq * 8;
    // B staging: arr = t>>7 (wave-uniform), row 0..31, chunk 0..3
    int barr = t >> 7;
    int br = (t >> 2) & 31, bq = t & 3;
    const u16* gB = (barr ? Bl : Bh) + (n0 + br) * 800 + bq * 8;
    u16* sB = (barr ? sBl : sBh);
    int bdst = br * 40 + bq * 8;

    f32x4 acc[2] = {};

    for (int k0 = 0; k0 < 800; k0 += 32) {
        *(uint4*)&sAh[adst] = *(const uint4*)(gAh + k0);
        *(uint4*)&sAl[adst] = *(const uint4*)(gAl + k0);
        *(uint4*)&sB[bdst]  = *(const uint4*)(gB + k0);
        __syncthreads();

        short8 a_h[2], a_l[2], b_h, b_l;
        #pragma unroll
        for (int f = 0; f < 2; f++) {
            int mi = (wm + f * 16 + lo4) * 40 + quad * 8;
            a_h[f] = *(const short8*)&sAh[mi];
            a_l[f] = *(const short8*)&sAl[mi];
        }
        {
            int ni = (wn + lo4) * 40 + quad * 8;
            b_h = *(const short8*)&sBh[ni];
            b_l = *(const short8*)&sBl[ni];
        }
        #pragma unroll
        for (int fm = 0; fm < 2; fm++) {
            acc[fm] = __builtin_amdgcn_mfma_f32_16x16x32_bf16(a_h[fm], b_h, acc[fm], 0, 0, 0);
            acc[fm] = __builtin_amdgcn_mfma_f32_16x16x32_bf16(a_h[fm], b_l, acc[fm], 0, 0, 0);
            acc[fm] = __builtin_amdgcn_mfma_f32_16x16x32_bf16(a_l[fm], b_h, acc[fm], 0, 0, 0);
        }
        __syncthreads();
    }

    // C/D layout: col = lane&15, row = quad*4 + reg (m89/m91, R6-validated)
    int n = n0 + wn + lo4;
    float bv = bias[n];
    #pragma unroll
    for (int fm = 0; fm < 2; fm++) {
        #pragma unroll
        for (int r = 0; r < 4; r++) {
            int m = m0 + wm + fm * 16 + quad * 4 + r;
            float v = acc[fm][r] + bv;
            C[m * 1024 + n] = fminf(fmaxf(v, 0.f), 1.f);
        }
    }
}

// ============================================================
// K3: per-row tail, one wave per row, 4 waves/block, float4 loads.
// Pair form: for k in [0,512): va=x0*x1*cc (w1[j][k]), vb=x0*cc
// (w1[j][k+512]). 64 lanes x float4 -> 2 iterations.
// ============================================================
__global__ __launch_bounds__(256) void k3_tail(
    const float* __restrict__ l0,  // (1024,1024)
    const float* __restrict__ w1,  // (15,1024)
    const float* __restrict__ b1,
    const float* __restrict__ w2,  // (32,15)
    const float* __restrict__ b2,
    const float* __restrict__ w3,  // (1,32)
    const float* __restrict__ b3,
    float* __restrict__ out)       // (1024,)
{
    int wave = threadIdx.x >> 6;
    int lane = threadIdx.x & 63;
    int b = blockIdx.x * 4 + wave;
    const float* row = l0 + b * 1024;
    const float cc = 0.9921875f;   // 127/128

    float acc[15];
    #pragma unroll
    for (int j = 0; j < 15; j++) acc[j] = 0.f;

    #pragma unroll
    for (int i = 0; i < 2; i++) {
        int k4 = (lane + i * 64) * 4;            // 0..508 step 4
        float4 x0 = *(const float4*)(row + k4);
        float4 x1 = *(const float4*)(row + k4 + 512);
        float4 va, vb;
        va.x = x0.x * x1.x * cc; va.y = x0.y * x1.y * cc;
        va.z = x0.z * x1.z * cc; va.w = x0.w * x1.w * cc;
        vb.x = x0.x * cc; vb.y = x0.y * cc;
        vb.z = x0.z * cc; vb.w = x0.w * cc;
        #pragma unroll
        for (int j = 0; j < 15; j++) {
            float4 wa = *(const float4*)(w1 + j * 1024 + k4);
            float4 wb = *(const float4*)(w1 + j * 1024 + k4 + 512);
            acc[j] = fmaf(va.x, wa.x, acc[j]); acc[j] = fmaf(va.y, wa.y, acc[j]);
            acc[j] = fmaf(va.z, wa.z, acc[j]); acc[j] = fmaf(va.w, wa.w, acc[j]);
            acc[j] = fmaf(vb.x, wb.x, acc[j]); acc[j] = fmaf(vb.y, wb.y, acc[j]);
            acc[j] = fmaf(vb.z, wb.z, acc[j]); acc[j] = fmaf(vb.w, wb.w, acc[j]);
        }
    }

    #pragma unroll
    for (int j = 0; j < 15; j++) {
        #pragma unroll
        for (int m = 32; m >= 1; m >>= 1)
            acc[j] += __shfl_xor(acc[j], m, 64);
    }
    float h1[15];
    #pragma unroll
    for (int j = 0; j < 15; j++) h1[j] = fmaxf(acc[j] + b1[j], 0.f);

    float contrib = 0.f;
    if (lane < 32) {
        float h2 = b2[lane];
        #pragma unroll
        for (int j = 0; j < 15; j++) h2 = fmaf(h1[j], w2[lane * 15 + j], h2);
        h2 = fmaxf(h2, 0.f);
        contrib = h2 * w3[lane];
    }
    #pragma unroll
    for (int m = 32; m >= 1; m >>= 1) contrib += __shfl_xor(contrib, m, 64);

    if (lane == 0) out[b] = contrib + b3[0];
}

// ============================================================
extern "C" void kernel_launch(void* const* d_in, const int* in_sizes, int n_in,
                              void* d_out, int out_size, void* d_ws, size_t ws_size,
                              hipStream_t stream) {
    const float* images = (const float*)d_in[0];
    const float* conv_w = (const float*)d_in[1];
    const float* ft_w   = (const float*)d_in[2];
    const float* ft_b   = (const float*)d_in[3];
    const float* w1     = (const float*)d_in[4];
    const float* b1     = (const float*)d_in[5];
    const float* w2     = (const float*)d_in[6];
    const float* b2     = (const float*)d_in[7];
    const float* w3     = (const float*)d_in[8];
    const float* b3     = (const float*)d_in[9];
    float* out = (float*)d_out;

    const int NV = 1024 * 800;                 // 819200
    u16* vh  = (u16*)d_ws;
    u16* vl  = vh + NV;
    u16* bth = vl + NV;
    u16* btl = bth + NV;
    float* l0 = (float*)(btl + NV);            // (1024,1024) f32

    k1_conv_split<<<1056, 256, 0, stream>>>(images, conv_w, ft_w, vh, vl, bth, btl);
    k2_mfma<<<dim3(32, 16), 256, 0, stream>>>(vh, vl, bth, btl, ft_b, l0);
    k3_tail<<<256, 256, 0, stream>>>(l0, w1, b1, w2, b2, w3, b3, out);
}

// Round 8
// 216.654 us; speedup vs baseline: 1.0591x; 1.0591x over previous
//
#include <hip/hip_runtime.h>

typedef unsigned short u16;
typedef unsigned int   u32;
typedef __attribute__((ext_vector_type(8))) short short8;   // 8 bf16
typedef __attribute__((ext_vector_type(4))) float f32x4;

__device__ __forceinline__ u16 f2bf(float f) {
    union { float f; u32 i; } v; v.f = f;
    u32 x = v.i;
    return (u16)((x + 0x7fffu + ((x >> 16) & 1u)) >> 16);   // RNE
}
__device__ __forceinline__ float bf2f(u16 u) {
    union { u32 i; float f; } v; v.i = ((u32)u) << 16; return v.f;
}

// ============================================================
// K0: transpose + hi/lo split of ft_w (800x1024 f32) ->
//     Bt_hi/Bt_lo (1024x800 bf16, n-major)   [R6-validated]
// ============================================================
__global__ __launch_bounds__(256) void k0_split(
    const float* __restrict__ ft_w,
    u16* __restrict__ bth, u16* __restrict__ btl)
{
    __shared__ float tile[32][33];
    int k0 = blockIdx.x * 32, n0 = blockIdx.y * 32;
    int tx = threadIdx.x & 31, ty = threadIdx.x >> 5;   // ty 0..7
    #pragma unroll
    for (int i = 0; i < 4; i++) {
        int k = ty + i * 8;
        tile[k][tx] = ft_w[(k0 + k) * 1024 + n0 + tx];
    }
    __syncthreads();
    #pragma unroll
    for (int i = 0; i < 4; i++) {
        int n = ty + i * 8;
        float wv = tile[tx][n];
        u16 hi = f2bf(wv);
        float lo = wv - bf2f(hi);
        bth[(n0 + n) * 800 + k0 + tx] = hi;
        btl[(n0 + n) * 800 + k0 + tx] = f2bf(lo);
    }
}

// ============================================================
// K1: conv + clip + sigmoid + mask -> hi/lo bf16   [R6-validated]
// ============================================================
__global__ __launch_bounds__(256) void k1_conv(
    const float* __restrict__ images,   // (1024,3,96,96)
    const float* __restrict__ conv_w,   // (8,3,3,3)
    u16* __restrict__ vh, u16* __restrict__ vl)   // (1024,800)
{
    __shared__ float img_s[3][29][96];
    __shared__ float w[216];

    int b = blockIdx.x;
    int t = threadIdx.x;
    if (t < 216) w[t] = conv_w[t];

    for (int i = t; i < 3 * 29 * 96; i += 256) {
        int ch  = i / (29 * 96);
        int rem = i - ch * (29 * 96);
        int lr  = rem / 96;
        int x   = rem - lr * 96;
        int ih  = 10 * ((lr + 1) / 3) + (lr + 1) % 3 - 1;
        img_s[ch][lr][x] = images[((b * 3 + ch) * 96 + ih) * 96 + x];
    }
    __syncthreads();

    for (int ridx = t; ridx < 800; ridx += 256) {
        int o  = ridx / 100;
        int p  = ridx - o * 100;
        int oh = p / 10;
        int ow = p - oh * 10;

        float sum = 0.0f;
        #pragma unroll
        for (int ic = 0; ic < 3; ic++) {
            const float* wc = &w[o * 27 + ic * 9];
            #pragma unroll
            for (int kh = 0; kh < 3; kh++) {
                int lr = 3 * oh + kh - 1;
                if (lr < 0) continue;
                #pragma unroll
                for (int kw = 0; kw < 3; kw++) {
                    int iw = ow * 10 + kw - 1;
                    if (iw < 0) continue;
                    sum = fmaf(img_s[ic][lr][iw], wc[kh * 3 + kw], sum);
                }
            }
        }
        float xc = fminf(fmaxf(sum, -1.0f), 1.0f);
        float binary = 1.0f / (1.0f + __expf(-10.0f * xc));
        float v = (binary > 0.5f) ? binary : 0.0f;
        u16 hi = f2bf(v);
        vh[b * 800 + ridx] = hi;
        vl[b * 800 + ridx] = f2bf(v - bf2f(hi));
    }
}

// ============================================================
// K2: split-bf16 MFMA GEMM, 64x64 tile, 4 waves, 2x2 frags
// [R6-validated: 215 us total, absmax 2.44e-4]
// ============================================================
__global__ __launch_bounds__(256) void k2_mfma(
    const u16* __restrict__ Ah, const u16* __restrict__ Al,   // (1024,800)
    const u16* __restrict__ Bh, const u16* __restrict__ Bl,   // (1024,800) n-major
    const float* __restrict__ bias,
    float* __restrict__ C)                                    // (1024,1024)
{
    __shared__ u16 sAh[64 * 40], sAl[64 * 40], sBh[64 * 40], sBl[64 * 40];
    int t = threadIdx.x;
    int m0 = blockIdx.y * 64, n0 = blockIdx.x * 64;
    int w = t >> 6, lane = t & 63;
    int quad = lane >> 4, lo4 = lane & 15;
    int wm = (w >> 1) * 32, wn = (w & 1) * 32;

    int sr = t >> 2;   // staging row 0..63
    int sq = t & 3;    // 8-elem chunk 0..3
    const u16* gAh = Ah + (m0 + sr) * 800 + sq * 8;
    const u16* gAl = Al + (m0 + sr) * 800 + sq * 8;
    const u16* gBh = Bh + (n0 + sr) * 800 + sq * 8;
    const u16* gBl = Bl + (n0 + sr) * 800 + sq * 8;
    int sdst = sr * 40 + sq * 8;

    f32x4 acc[2][2] = {};

    for (int k0 = 0; k0 < 800; k0 += 32) {
        *(uint4*)&sAh[sdst] = *(const uint4*)(gAh + k0);
        *(uint4*)&sAl[sdst] = *(const uint4*)(gAl + k0);
        *(uint4*)&sBh[sdst] = *(const uint4*)(gBh + k0);
        *(uint4*)&sBl[sdst] = *(const uint4*)(gBl + k0);
        __syncthreads();

        short8 a_h[2], a_l[2], b_h[2], b_l[2];
        #pragma unroll
        for (int f = 0; f < 2; f++) {
            int mi = (wm + f * 16 + lo4) * 40 + quad * 8;
            a_h[f] = *(const short8*)&sAh[mi];
            a_l[f] = *(const short8*)&sAl[mi];
            int ni = (wn + f * 16 + lo4) * 40 + quad * 8;
            b_h[f] = *(const short8*)&sBh[ni];
            b_l[f] = *(const short8*)&sBl[ni];
        }
        #pragma unroll
        for (int fm = 0; fm < 2; fm++)
            #pragma unroll
            for (int fn = 0; fn < 2; fn++) {
                acc[fm][fn] = __builtin_amdgcn_mfma_f32_16x16x32_bf16(a_h[fm], b_h[fn], acc[fm][fn], 0, 0, 0);
                acc[fm][fn] = __builtin_amdgcn_mfma_f32_16x16x32_bf16(a_h[fm], b_l[fn], acc[fm][fn], 0, 0, 0);
                acc[fm][fn] = __builtin_amdgcn_mfma_f32_16x16x32_bf16(a_l[fm], b_h[fn], acc[fm][fn], 0, 0, 0);
            }
        __syncthreads();
    }

    // C/D layout: col = lane&15, row = quad*4 + reg
    #pragma unroll
    for (int fm = 0; fm < 2; fm++) {
        #pragma unroll
        for (int fn = 0; fn < 2; fn++) {
            int n = n0 + wn + fn * 16 + lo4;
            float bv = bias[n];
            #pragma unroll
            for (int r = 0; r < 4; r++) {
                int m = m0 + wm + fm * 16 + quad * 4 + r;
                float v = acc[fm][fn][r] + bv;
                C[m * 1024 + n] = fminf(fmaxf(v, 0.f), 1.f);
            }
        }
    }
}

// ============================================================
// K3: per-row tail, one wave per row, 4 waves/block, float4 loads.
// (only delta vs R6 — isolating its effect)
// ============================================================
__global__ __launch_bounds__(256) void k3_tail(
    const float* __restrict__ l0,  // (1024,1024)
    const float* __restrict__ w1,  // (15,1024)
    const float* __restrict__ b1,
    const float* __restrict__ w2,  // (32,15)
    const float* __restrict__ b2,
    const float* __restrict__ w3,  // (1,32)
    const float* __restrict__ b3,
    float* __restrict__ out)       // (1024,)
{
    int wave = threadIdx.x >> 6;
    int lane = threadIdx.x & 63;
    int b = blockIdx.x * 4 + wave;
    const float* row = l0 + b * 1024;
    const float cc = 0.9921875f;   // 127/128

    float acc[15];
    #pragma unroll
    for (int j = 0; j < 15; j++) acc[j] = 0.f;

    #pragma unroll
    for (int i = 0; i < 2; i++) {
        int k4 = (lane + i * 64) * 4;            // 0..508 step 4
        float4 x0 = *(const float4*)(row + k4);
        float4 x1 = *(const float4*)(row + k4 + 512);
        float4 va, vb;
        va.x = x0.x * x1.x * cc; va.y = x0.y * x1.y * cc;
        va.z = x0.z * x1.z * cc; va.w = x0.w * x1.w * cc;
        vb.x = x0.x * cc; vb.y = x0.y * cc;
        vb.z = x0.z * cc; vb.w = x0.w * cc;
        #pragma unroll
        for (int j = 0; j < 15; j++) {
            float4 wa = *(const float4*)(w1 + j * 1024 + k4);
            float4 wb = *(const float4*)(w1 + j * 1024 + k4 + 512);
            acc[j] = fmaf(va.x, wa.x, acc[j]); acc[j] = fmaf(va.y, wa.y, acc[j]);
            acc[j] = fmaf(va.z, wa.z, acc[j]); acc[j] = fmaf(va.w, wa.w, acc[j]);
            acc[j] = fmaf(vb.x, wb.x, acc[j]); acc[j] = fmaf(vb.y, wb.y, acc[j]);
            acc[j] = fmaf(vb.z, wb.z, acc[j]); acc[j] = fmaf(vb.w, wb.w, acc[j]);
        }
    }

    #pragma unroll
    for (int j = 0; j < 15; j++) {
        #pragma unroll
        for (int m = 32; m >= 1; m >>= 1)
            acc[j] += __shfl_xor(acc[j], m, 64);
    }
    float h1[15];
    #pragma unroll
    for (int j = 0; j < 15; j++) h1[j] = fmaxf(acc[j] + b1[j], 0.f);

    float contrib = 0.f;
    if (lane < 32) {
        float h2 = b2[lane];
        #pragma unroll
        for (int j = 0; j < 15; j++) h2 = fmaf(h1[j], w2[lane * 15 + j], h2);
        h2 = fmaxf(h2, 0.f);
        contrib = h2 * w3[lane];
    }
    #pragma unroll
    for (int m = 32; m >= 1; m >>= 1) contrib += __shfl_xor(contrib, m, 64);

    if (lane == 0) out[b] = contrib + b3[0];
}

// ============================================================
extern "C" void kernel_launch(void* const* d_in, const int* in_sizes, int n_in,
                              void* d_out, int out_size, void* d_ws, size_t ws_size,
                              hipStream_t stream) {
    const float* images = (const float*)d_in[0];
    const float* conv_w = (const float*)d_in[1];
    const float* ft_w   = (const float*)d_in[2];
    const float* ft_b   = (const float*)d_in[3];
    const float* w1     = (const float*)d_in[4];
    const float* b1     = (const float*)d_in[5];
    const float* w2     = (const float*)d_in[6];
    const float* b2     = (const float*)d_in[7];
    const float* w3     = (const float*)d_in[8];
    const float* b3     = (const float*)d_in[9];
    float* out = (float*)d_out;

    const int NV = 1024 * 800;                 // 819200
    u16* vh  = (u16*)d_ws;
    u16* vl  = vh + NV;
    u16* bth = vl + NV;
    u16* btl = bth + NV;
    float* l0 = (float*)(btl + NV);            // (1024,1024) f32

    k0_split<<<dim3(25, 32), 256, 0, stream>>>(ft_w, bth, btl);
    k1_conv<<<1024, 256, 0, stream>>>(images, conv_w, vh, vl);
    k2_mfma<<<dim3(16, 16), 256, 0, stream>>>(vh, vl, bth, btl, ft_b, l0);
    k3_tail<<<256, 256, 0, stream>>>(l0, w1, b1, w2, b2, w3, b3, out);
}

// Round 9
// 212.440 us; speedup vs baseline: 1.0801x; 1.0198x over previous
//
#include <hip/hip_runtime.h>

typedef unsigned short u16;
typedef unsigned int   u32;
typedef __attribute__((ext_vector_type(8))) short short8;   // 8 bf16
typedef __attribute__((ext_vector_type(4))) float f32x4;

__device__ __forceinline__ u16 f2bf(float f) {
    union { float f; u32 i; } v; v.f = f;
    u32 x = v.i;
    return (u16)((x + 0x7fffu + ((x >> 16) & 1u)) >> 16);   // RNE
}
__device__ __forceinline__ float bf2f(u16 u) {
    union { u32 i; float f; } v; v.i = ((u32)u) << 16; return v.f;
}

// ============================================================
// K1 (fused, full-parallel): blocks [0,1024): conv path (R6-validated).
// Blocks [1024,1824): ft_w transpose+split, ONE 32x32 tile per block
// (exact k0 structure — R7's serialized-loop mistake not repeated).
// ============================================================
__global__ __launch_bounds__(256) void k1_fused(
    const float* __restrict__ images,   // (1024,3,96,96)
    const float* __restrict__ conv_w,   // (8,3,3,3)
    const float* __restrict__ ft_w,     // (800,1024)
    u16* __restrict__ vh, u16* __restrict__ vl,     // (1024,800)
    u16* __restrict__ bth, u16* __restrict__ btl)   // (1024,800) n-major
{
    __shared__ float img_s[3][29][96];
    __shared__ float w[216];
    __shared__ float tile[32][33];

    int t = threadIdx.x;

    if (blockIdx.x >= 1024) {
        // ---- one 32x32 transpose tile; tid 1024..1823 -> (kb, nb) ----
        int bid = blockIdx.x - 1024;       // 0..799
        int kb = bid / 32, nb = bid - kb * 32;
        int k0 = kb * 32, n0 = nb * 32;
        int tx = t & 31, ty = t >> 5;      // ty 0..7
        #pragma unroll
        for (int i = 0; i < 4; i++) {
            int k = ty + i * 8;
            tile[k][tx] = ft_w[(k0 + k) * 1024 + n0 + tx];
        }
        __syncthreads();
        #pragma unroll
        for (int i = 0; i < 4; i++) {
            int n = ty + i * 8;
            float wv = tile[tx][n];
            u16 hi = f2bf(wv);
            float lo = wv - bf2f(hi);
            bth[(n0 + n) * 800 + k0 + tx] = hi;
            btl[(n0 + n) * 800 + k0 + tx] = f2bf(lo);
        }
        return;
    }

    // ---- conv path: one block per image (R6-validated) ----
    int b = blockIdx.x;
    if (t < 216) w[t] = conv_w[t];

    for (int i = t; i < 3 * 29 * 96; i += 256) {
        int ch  = i / (29 * 96);
        int rem = i - ch * (29 * 96);
        int lr  = rem / 96;
        int x   = rem - lr * 96;
        int ih  = 10 * ((lr + 1) / 3) + (lr + 1) % 3 - 1;
        img_s[ch][lr][x] = images[((b * 3 + ch) * 96 + ih) * 96 + x];
    }
    __syncthreads();

    for (int ridx = t; ridx < 800; ridx += 256) {
        int o  = ridx / 100;
        int p  = ridx - o * 100;
        int oh = p / 10;
        int ow = p - oh * 10;

        float sum = 0.0f;
        #pragma unroll
        for (int ic = 0; ic < 3; ic++) {
            const float* wc = &w[o * 27 + ic * 9];
            #pragma unroll
            for (int kh = 0; kh < 3; kh++) {
                int lr = 3 * oh + kh - 1;
                if (lr < 0) continue;
                #pragma unroll
                for (int kw = 0; kw < 3; kw++) {
                    int iw = ow * 10 + kw - 1;
                    if (iw < 0) continue;
                    sum = fmaf(img_s[ic][lr][iw], wc[kh * 3 + kw], sum);
                }
            }
        }
        float xc = fminf(fmaxf(sum, -1.0f), 1.0f);
        float binary = 1.0f / (1.0f + __expf(-10.0f * xc));
        float v = (binary > 0.5f) ? binary : 0.0f;
        u16 hi = f2bf(v);
        vh[b * 800 + ridx] = hi;
        vl[b * 800 + ridx] = f2bf(v - bf2f(hi));
    }
}

// ============================================================
// K2: split-bf16 MFMA GEMM, 64x64 tile, 4 waves, 2x2 frags
// [R6/R8-validated: absmax 2.44e-4]
// ============================================================
__global__ __launch_bounds__(256) void k2_mfma(
    const u16* __restrict__ Ah, const u16* __restrict__ Al,   // (1024,800)
    const u16* __restrict__ Bh, const u16* __restrict__ Bl,   // (1024,800) n-major
    const float* __restrict__ bias,
    float* __restrict__ C)                                    // (1024,1024)
{
    __shared__ u16 sAh[64 * 40], sAl[64 * 40], sBh[64 * 40], sBl[64 * 40];
    int t = threadIdx.x;
    int m0 = blockIdx.y * 64, n0 = blockIdx.x * 64;
    int w = t >> 6, lane = t & 63;
    int quad = lane >> 4, lo4 = lane & 15;
    int wm = (w >> 1) * 32, wn = (w & 1) * 32;

    int sr = t >> 2;   // staging row 0..63
    int sq = t & 3;    // 8-elem chunk 0..3
    const u16* gAh = Ah + (m0 + sr) * 800 + sq * 8;
    const u16* gAl = Al + (m0 + sr) * 800 + sq * 8;
    const u16* gBh = Bh + (n0 + sr) * 800 + sq * 8;
    const u16* gBl = Bl + (n0 + sr) * 800 + sq * 8;
    int sdst = sr * 40 + sq * 8;

    f32x4 acc[2][2] = {};

    for (int k0 = 0; k0 < 800; k0 += 32) {
        *(uint4*)&sAh[sdst] = *(const uint4*)(gAh + k0);
        *(uint4*)&sAl[sdst] = *(const uint4*)(gAl + k0);
        *(uint4*)&sBh[sdst] = *(const uint4*)(gBh + k0);
        *(uint4*)&sBl[sdst] = *(const uint4*)(gBl + k0);
        __syncthreads();

        short8 a_h[2], a_l[2], b_h[2], b_l[2];
        #pragma unroll
        for (int f = 0; f < 2; f++) {
            int mi = (wm + f * 16 + lo4) * 40 + quad * 8;
            a_h[f] = *(const short8*)&sAh[mi];
            a_l[f] = *(const short8*)&sAl[mi];
            int ni = (wn + f * 16 + lo4) * 40 + quad * 8;
            b_h[f] = *(const short8*)&sBh[ni];
            b_l[f] = *(const short8*)&sBl[ni];
        }
        #pragma unroll
        for (int fm = 0; fm < 2; fm++)
            #pragma unroll
            for (int fn = 0; fn < 2; fn++) {
                acc[fm][fn] = __builtin_amdgcn_mfma_f32_16x16x32_bf16(a_h[fm], b_h[fn], acc[fm][fn], 0, 0, 0);
                acc[fm][fn] = __builtin_amdgcn_mfma_f32_16x16x32_bf16(a_h[fm], b_l[fn], acc[fm][fn], 0, 0, 0);
                acc[fm][fn] = __builtin_amdgcn_mfma_f32_16x16x32_bf16(a_l[fm], b_h[fn], acc[fm][fn], 0, 0, 0);
            }
        __syncthreads();
    }

    // C/D layout: col = lane&15, row = quad*4 + reg
    #pragma unroll
    for (int fm = 0; fm < 2; fm++) {
        #pragma unroll
        for (int fn = 0; fn < 2; fn++) {
            int n = n0 + wn + fn * 16 + lo4;
            float bv = bias[n];
            #pragma unroll
            for (int r = 0; r < 4; r++) {
                int m = m0 + wm + fm * 16 + quad * 4 + r;
                float v = acc[fm][fn][r] + bv;
                C[m * 1024 + n] = fminf(fmaxf(v, 0.f), 1.f);
            }
        }
    }
}

// ============================================================
// K3: per-row tail, one wave per row, 4 waves/block, float4 loads.
// [R8-validated]
// ============================================================
__global__ __launch_bounds__(256) void k3_tail(
    const float* __restrict__ l0,  // (1024,1024)
    const float* __restrict__ w1,  // (15,1024)
    const float* __restrict__ b1,
    const float* __restrict__ w2,  // (32,15)
    const float* __restrict__ b2,
    const float* __restrict__ w3,  // (1,32)
    const float* __restrict__ b3,
    float* __restrict__ out)       // (1024,)
{
    int wave = threadIdx.x >> 6;
    int lane = threadIdx.x & 63;
    int b = blockIdx.x * 4 + wave;
    const float* row = l0 + b * 1024;
    const float cc = 0.9921875f;   // 127/128

    float acc[15];
    #pragma unroll
    for (int j = 0; j < 15; j++) acc[j] = 0.f;

    #pragma unroll
    for (int i = 0; i < 2; i++) {
        int k4 = (lane + i * 64) * 4;            // 0..508 step 4
        float4 x0 = *(const float4*)(row + k4);
        float4 x1 = *(const float4*)(row + k4 + 512);
        float4 va, vb;
        va.x = x0.x * x1.x * cc; va.y = x0.y * x1.y * cc;
        va.z = x0.z * x1.z * cc; va.w = x0.w * x1.w * cc;
        vb.x = x0.x * cc; vb.y = x0.y * cc;
        vb.z = x0.z * cc; vb.w = x0.w * cc;
        #pragma unroll
        for (int j = 0; j < 15; j++) {
            float4 wa = *(const float4*)(w1 + j * 1024 + k4);
            float4 wb = *(const float4*)(w1 + j * 1024 + k4 + 512);
            acc[j] = fmaf(va.x, wa.x, acc[j]); acc[j] = fmaf(va.y, wa.y, acc[j]);
            acc[j] = fmaf(va.z, wa.z, acc[j]); acc[j] = fmaf(va.w, wa.w, acc[j]);
            acc[j] = fmaf(vb.x, wb.x, acc[j]); acc[j] = fmaf(vb.y, wb.y, acc[j]);
            acc[j] = fmaf(vb.z, wb.z, acc[j]); acc[j] = fmaf(vb.w, wb.w, acc[j]);
        }
    }

    #pragma unroll
    for (int j = 0; j < 15; j++) {
        #pragma unroll
        for (int m = 32; m >= 1; m >>= 1)
            acc[j] += __shfl_xor(acc[j], m, 64);
    }
    float h1[15];
    #pragma unroll
    for (int j = 0; j < 15; j++) h1[j] = fmaxf(acc[j] + b1[j], 0.f);

    float contrib = 0.f;
    if (lane < 32) {
        float h2 = b2[lane];
        #pragma unroll
        for (int j = 0; j < 15; j++) h2 = fmaf(h1[j], w2[lane * 15 + j], h2);
        h2 = fmaxf(h2, 0.f);
        contrib = h2 * w3[lane];
    }
    #pragma unroll
    for (int m = 32; m >= 1; m >>= 1) contrib += __shfl_xor(contrib, m, 64);

    if (lane == 0) out[b] = contrib + b3[0];
}

// ============================================================
extern "C" void kernel_launch(void* const* d_in, const int* in_sizes, int n_in,
                              void* d_out, int out_size, void* d_ws, size_t ws_size,
                              hipStream_t stream) {
    const float* images = (const float*)d_in[0];
    const float* conv_w = (const float*)d_in[1];
    const float* ft_w   = (const float*)d_in[2];
    const float* ft_b   = (const float*)d_in[3];
    const float* w1     = (const float*)d_in[4];
    const float* b1     = (const float*)d_in[5];
    const float* w2     = (const float*)d_in[6];
    const float* b2     = (const float*)d_in[7];
    const float* w3     = (const float*)d_in[8];
    const float* b3     = (const float*)d_in[9];
    float* out = (float*)d_out;

    const int NV = 1024 * 800;                 // 819200
    u16* vh  = (u16*)d_ws;
    u16* vl  = vh + NV;
    u16* bth = vl + NV;
    u16* btl = bth + NV;
    float* l0 = (float*)(btl + NV);            // (1024,1024) f32

    k1_fused<<<1824, 256, 0, stream>>>(images, conv_w, ft_w, vh, vl, bth, btl);
    k2_mfma<<<dim3(16, 16), 256, 0, stream>>>(vh, vl, bth, btl, ft_b, l0);
    k3_tail<<<256, 256, 0, stream>>>(l0, w1, b1, w2, b2, w3, b3, out);
}

// Round 10
// 209.464 us; speedup vs baseline: 1.0955x; 1.0142x over previous
//
#include <hip/hip_runtime.h>

typedef unsigned short u16;
typedef unsigned int   u32;
typedef __attribute__((ext_vector_type(8))) short short8;   // 8 bf16
typedef __attribute__((ext_vector_type(4))) float f32x4;

__device__ __forceinline__ u16 f2bf(float f) {
    union { float f; u32 i; } v; v.f = f;
    u32 x = v.i;
    return (u16)((x + 0x7fffu + ((x >> 16) & 1u)) >> 16);   // RNE
}
__device__ __forceinline__ float bf2f(u16 u) {
    union { u32 i; float f; } v; v.i = ((u32)u) << 16; return v.f;
}

// ============================================================
// K1 (fused, full-parallel) [R9-validated: 212.4 us]
// blocks [0,1024): conv; blocks [1024,1824): one 32x32 ft_w
// transpose+split tile per block.
// ============================================================
__global__ __launch_bounds__(256) void k1_fused(
    const float* __restrict__ images,   // (1024,3,96,96)
    const float* __restrict__ conv_w,   // (8,3,3,3)
    const float* __restrict__ ft_w,     // (800,1024)
    u16* __restrict__ vh, u16* __restrict__ vl,     // (1024,800)
    u16* __restrict__ bth, u16* __restrict__ btl)   // (1024,800) n-major
{
    __shared__ float img_s[3][29][96];
    __shared__ float w[216];
    __shared__ float tile[32][33];

    int t = threadIdx.x;

    if (blockIdx.x >= 1024) {
        int bid = blockIdx.x - 1024;       // 0..799
        int kb = bid / 32, nb = bid - kb * 32;
        int k0 = kb * 32, n0 = nb * 32;
        int tx = t & 31, ty = t >> 5;      // ty 0..7
        #pragma unroll
        for (int i = 0; i < 4; i++) {
            int k = ty + i * 8;
            tile[k][tx] = ft_w[(k0 + k) * 1024 + n0 + tx];
        }
        __syncthreads();
        #pragma unroll
        for (int i = 0; i < 4; i++) {
            int n = ty + i * 8;
            float wv = tile[tx][n];
            u16 hi = f2bf(wv);
            float lo = wv - bf2f(hi);
            bth[(n0 + n) * 800 + k0 + tx] = hi;
            btl[(n0 + n) * 800 + k0 + tx] = f2bf(lo);
        }
        return;
    }

    int b = blockIdx.x;
    if (t < 216) w[t] = conv_w[t];

    for (int i = t; i < 3 * 29 * 96; i += 256) {
        int ch  = i / (29 * 96);
        int rem = i - ch * (29 * 96);
        int lr  = rem / 96;
        int x   = rem - lr * 96;
        int ih  = 10 * ((lr + 1) / 3) + (lr + 1) % 3 - 1;
        img_s[ch][lr][x] = images[((b * 3 + ch) * 96 + ih) * 96 + x];
    }
    __syncthreads();

    for (int ridx = t; ridx < 800; ridx += 256) {
        int o  = ridx / 100;
        int p  = ridx - o * 100;
        int oh = p / 10;
        int ow = p - oh * 10;

        float sum = 0.0f;
        #pragma unroll
        for (int ic = 0; ic < 3; ic++) {
            const float* wc = &w[o * 27 + ic * 9];
            #pragma unroll
            for (int kh = 0; kh < 3; kh++) {
                int lr = 3 * oh + kh - 1;
                if (lr < 0) continue;
                #pragma unroll
                for (int kw = 0; kw < 3; kw++) {
                    int iw = ow * 10 + kw - 1;
                    if (iw < 0) continue;
                    sum = fmaf(img_s[ic][lr][iw], wc[kh * 3 + kw], sum);
                }
            }
        }
        float xc = fminf(fmaxf(sum, -1.0f), 1.0f);
        float binary = 1.0f / (1.0f + __expf(-10.0f * xc));
        float v = (binary > 0.5f) ? binary : 0.0f;
        u16 hi = f2bf(v);
        vh[b * 800 + ridx] = hi;
        vl[b * 800 + ridx] = f2bf(v - bf2f(hi));
    }
}

// ============================================================
// K2: split-bf16 MFMA GEMM, 64x64 tile, 4 waves, 2x2 frags,
// NOW with register-prefetch pipelining (single LDS buffer):
// tile k+1's global loads issue right after the first barrier and
// are consumed at the next iteration's LDS writes — MFMA section
// hides the load latency (1 block/CU -> no TLP to hide it otherwise).
// ============================================================
__global__ __launch_bounds__(256) void k2_mfma(
    const u16* __restrict__ Ah, const u16* __restrict__ Al,   // (1024,800)
    const u16* __restrict__ Bh, const u16* __restrict__ Bl,   // (1024,800) n-major
    const float* __restrict__ bias,
    float* __restrict__ C)                                    // (1024,1024)
{
    __shared__ u16 sAh[64 * 40], sAl[64 * 40], sBh[64 * 40], sBl[64 * 40];
    int t = threadIdx.x;
    int m0 = blockIdx.y * 64, n0 = blockIdx.x * 64;
    int w = t >> 6, lane = t & 63;
    int quad = lane >> 4, lo4 = lane & 15;
    int wm = (w >> 1) * 32, wn = (w & 1) * 32;

    int sr = t >> 2;   // staging row 0..63
    int sq = t & 3;    // 8-elem chunk 0..3
    const u16* gAh = Ah + (m0 + sr) * 800 + sq * 8;
    const u16* gAl = Al + (m0 + sr) * 800 + sq * 8;
    const u16* gBh = Bh + (n0 + sr) * 800 + sq * 8;
    const u16* gBl = Bl + (n0 + sr) * 800 + sq * 8;
    int sdst = sr * 40 + sq * 8;

    f32x4 acc[2][2] = {};

    uint4 rAh = *(const uint4*)(gAh);
    uint4 rAl = *(const uint4*)(gAl);
    uint4 rBh = *(const uint4*)(gBh);
    uint4 rBl = *(const uint4*)(gBl);

    for (int k0 = 0; k0 < 800; k0 += 32) {
        *(uint4*)&sAh[sdst] = rAh;
        *(uint4*)&sAl[sdst] = rAl;
        *(uint4*)&sBh[sdst] = rBh;
        *(uint4*)&sBl[sdst] = rBl;
        __syncthreads();

        if (k0 + 32 < 800) {               // prefetch next tile
            rAh = *(const uint4*)(gAh + k0 + 32);
            rAl = *(const uint4*)(gAl + k0 + 32);
            rBh = *(const uint4*)(gBh + k0 + 32);
            rBl = *(const uint4*)(gBl + k0 + 32);
        }

        short8 a_h[2], a_l[2], b_h[2], b_l[2];
        #pragma unroll
        for (int f = 0; f < 2; f++) {
            int mi = (wm + f * 16 + lo4) * 40 + quad * 8;
            a_h[f] = *(const short8*)&sAh[mi];
            a_l[f] = *(const short8*)&sAl[mi];
            int ni = (wn + f * 16 + lo4) * 40 + quad * 8;
            b_h[f] = *(const short8*)&sBh[ni];
            b_l[f] = *(const short8*)&sBl[ni];
        }
        #pragma unroll
        for (int fm = 0; fm < 2; fm++)
            #pragma unroll
            for (int fn = 0; fn < 2; fn++) {
                acc[fm][fn] = __builtin_amdgcn_mfma_f32_16x16x32_bf16(a_h[fm], b_h[fn], acc[fm][fn], 0, 0, 0);
                acc[fm][fn] = __builtin_amdgcn_mfma_f32_16x16x32_bf16(a_h[fm], b_l[fn], acc[fm][fn], 0, 0, 0);
                acc[fm][fn] = __builtin_amdgcn_mfma_f32_16x16x32_bf16(a_l[fm], b_h[fn], acc[fm][fn], 0, 0, 0);
            }
        __syncthreads();
    }

    // C/D layout: col = lane&15, row = quad*4 + reg
    #pragma unroll
    for (int fm = 0; fm < 2; fm++) {
        #pragma unroll
        for (int fn = 0; fn < 2; fn++) {
            int n = n0 + wn + fn * 16 + lo4;
            float bv = bias[n];
            #pragma unroll
            for (int r = 0; r < 4; r++) {
                int m = m0 + wm + fm * 16 + quad * 4 + r;
                float v = acc[fm][fn][r] + bv;
                C[m * 1024 + n] = fminf(fmaxf(v, 0.f), 1.f);
            }
        }
    }
}

// ============================================================
// K3: per-row tail, one wave per row, 4 waves/block, float4 loads.
// [R8/R9-validated]
// ============================================================
__global__ __launch_bounds__(256) void k3_tail(
    const float* __restrict__ l0,  // (1024,1024)
    const float* __restrict__ w1,  // (15,1024)
    const float* __restrict__ b1,
    const float* __restrict__ w2,  // (32,15)
    const float* __restrict__ b2,
    const float* __restrict__ w3,  // (1,32)
    const float* __restrict__ b3,
    float* __restrict__ out)       // (1024,)
{
    int wave = threadIdx.x >> 6;
    int lane = threadIdx.x & 63;
    int b = blockIdx.x * 4 + wave;
    const float* row = l0 + b * 1024;
    const float cc = 0.9921875f;   // 127/128

    float acc[15];
    #pragma unroll
    for (int j = 0; j < 15; j++) acc[j] = 0.f;

    #pragma unroll
    for (int i = 0; i < 2; i++) {
        int k4 = (lane + i * 64) * 4;            // 0..508 step 4
        float4 x0 = *(const float4*)(row + k4);
        float4 x1 = *(const float4*)(row + k4 + 512);
        float4 va, vb;
        va.x = x0.x * x1.x * cc; va.y = x0.y * x1.y * cc;
        va.z = x0.z * x1.z * cc; va.w = x0.w * x1.w * cc;
        vb.x = x0.x * cc; vb.y = x0.y * cc;
        vb.z = x0.z * cc; vb.w = x0.w * cc;
        #pragma unroll
        for (int j = 0; j < 15; j++) {
            float4 wa = *(const float4*)(w1 + j * 1024 + k4);
            float4 wb = *(const float4*)(w1 + j * 1024 + k4 + 512);
            acc[j] = fmaf(va.x, wa.x, acc[j]); acc[j] = fmaf(va.y, wa.y, acc[j]);
            acc[j] = fmaf(va.z, wa.z, acc[j]); acc[j] = fmaf(va.w, wa.w, acc[j]);
            acc[j] = fmaf(vb.x, wb.x, acc[j]); acc[j] = fmaf(vb.y, wb.y, acc[j]);
            acc[j] = fmaf(vb.z, wb.z, acc[j]); acc[j] = fmaf(vb.w, wb.w, acc[j]);
        }
    }

    #pragma unroll
    for (int j = 0; j < 15; j++) {
        #pragma unroll
        for (int m = 32; m >= 1; m >>= 1)
            acc[j] += __shfl_xor(acc[j], m, 64);
    }
    float h1[15];
    #pragma unroll
    for (int j = 0; j < 15; j++) h1[j] = fmaxf(acc[j] + b1[j], 0.f);

    float contrib = 0.f;
    if (lane < 32) {
        float h2 = b2[lane];
        #pragma unroll
        for (int j = 0; j < 15; j++) h2 = fmaf(h1[j], w2[lane * 15 + j], h2);
        h2 = fmaxf(h2, 0.f);
        contrib = h2 * w3[lane];
    }
    #pragma unroll
    for (int m = 32; m >= 1; m >>= 1) contrib += __shfl_xor(contrib, m, 64);

    if (lane == 0) out[b] = contrib + b3[0];
}

// ============================================================
extern "C" void kernel_launch(void* const* d_in, const int* in_sizes, int n_in,
                              void* d_out, int out_size, void* d_ws, size_t ws_size,
                              hipStream_t stream) {
    const float* images = (const float*)d_in[0];
    const float* conv_w = (const float*)d_in[1];
    const float* ft_w   = (const float*)d_in[2];
    const float* ft_b   = (const float*)d_in[3];
    const float* w1     = (const float*)d_in[4];
    const float* b1     = (const float*)d_in[5];
    const float* w2     = (const float*)d_in[6];
    const float* b2     = (const float*)d_in[7];
    const float* w3     = (const float*)d_in[8];
    const float* b3     = (const float*)d_in[9];
    float* out = (float*)d_out;

    const int NV = 1024 * 800;                 // 819200
    u16* vh  = (u16*)d_ws;
    u16* vl  = vh + NV;
    u16* bth = vl + NV;
    u16* btl = bth + NV;
    float* l0 = (float*)(btl + NV);            // (1024,1024) f32

    k1_fused<<<1824, 256, 0, stream>>>(images, conv_w, ft_w, vh, vl, bth, btl);
    k2_mfma<<<dim3(16, 16), 256, 0, stream>>>(vh, vl, bth, btl, ft_b, l0);
    k3_tail<<<256, 256, 0, stream>>>(l0, w1, b1, w2, b2, w3, b3, out);
}